// Round 1
// baseline (369.717 us; speedup 1.0000x reference)
//
#include <hip/hip_runtime.h>
#include <hip/hip_bf16.h>

typedef __attribute__((ext_vector_type(4))) float f32x4;
typedef __attribute__((ext_vector_type(8))) short bf16x8;
typedef __attribute__((ext_vector_type(4))) unsigned short u16x4;

// B=2, S=2048, D=1024, H=16, HD=64
#define SB 2048
#define DD 1024
#define NH 16
#define HD 64
#define BH 32   // B*H

static __device__ __forceinline__ unsigned short f2bf(float f) {
    union { float f; unsigned int u; } v; v.f = f;
    unsigned int lsb = (v.u >> 16) & 1u;
    v.u += 0x7fffu + lsb;           // round-to-nearest-even (inputs finite)
    return (unsigned short)(v.u >> 16);
}

// ---------------- Projection GEMM: C[4096,1024] = X[4096,1024] @ W[1024,1024]^T ----------------
// z=0: W=Wq, write qbf[bh][s][e] ; z=1: W=Wv, write vt[bh][e][s]
#define BM 128
#define BN 128
#define BK 32
#define LDP 56   // padded LDS row stride (bf16): 112B, 16B-aligned, 2-way bank alias (free)

__global__ __launch_bounds__(256) void proj_kernel(
    const float* __restrict__ X,
    const float* __restrict__ Wq,
    const float* __restrict__ Wv,
    unsigned short* __restrict__ qbf,   // [32][2048][64]
    unsigned short* __restrict__ vt)    // [32][64][2048]
{
    __shared__ unsigned short As[BM * LDP];
    __shared__ unsigned short Bs[BN * LDP];
    const int z  = blockIdx.z;
    const float* __restrict__ W = z ? Wv : Wq;
    const int m0 = blockIdx.y * BM;
    const int n0 = blockIdx.x * BN;
    const int tid  = threadIdx.x;
    const int wave = tid >> 6;
    const int lane = tid & 63;
    const int wr = wave >> 1, wc = wave & 1;      // 2x2 waves, each owns 64x64
    const int lrow = lane & 15, lk = (lane >> 4) * 8;

    f32x4 acc[4][4] = {};   // [mf][nf]

    for (int k0 = 0; k0 < DD; k0 += BK) {
        // stage A(128x32) and B(128x32), converting f32->bf16
        #pragma unroll
        for (int p = 0; p < 4; ++p) {
            int idx = p * 256 + tid;       // 0..1023
            int r   = idx >> 3;            // 0..127
            int c4  = (idx & 7) * 4;       // 0..28
            f32x4 a = *reinterpret_cast<const f32x4*>(X + (size_t)(m0 + r) * DD + k0 + c4);
            f32x4 b = *reinterpret_cast<const f32x4*>(W + (size_t)(n0 + r) * DD + k0 + c4);
            u16x4 pa, pb;
            #pragma unroll
            for (int j = 0; j < 4; ++j) { pa[j] = f2bf(a[j]); pb[j] = f2bf(b[j]); }
            *reinterpret_cast<u16x4*>(&As[r * LDP + c4]) = pa;
            *reinterpret_cast<u16x4*>(&Bs[r * LDP + c4]) = pb;
        }
        __syncthreads();

        bf16x8 af[4], bf[4];
        #pragma unroll
        for (int mf = 0; mf < 4; ++mf)
            af[mf] = *reinterpret_cast<const bf16x8*>(&As[(wr * 64 + mf * 16 + lrow) * LDP + lk]);
        #pragma unroll
        for (int nf = 0; nf < 4; ++nf)
            bf[nf] = *reinterpret_cast<const bf16x8*>(&Bs[(wc * 64 + nf * 16 + lrow) * LDP + lk]);
        #pragma unroll
        for (int mf = 0; mf < 4; ++mf)
            #pragma unroll
            for (int nf = 0; nf < 4; ++nf)
                acc[mf][nf] = __builtin_amdgcn_mfma_f32_16x16x32_bf16(af[mf], bf[nf], acc[mf][nf], 0, 0, 0);
        __syncthreads();
    }

    // epilogue: C/D layout col=lane&15, row=(lane>>4)*4+reg  [verified m89]
    const int lcol = lane & 15, lr4 = (lane >> 4) * 4;
    #pragma unroll
    for (int mf = 0; mf < 4; ++mf) {
        #pragma unroll
        for (int nf = 0; nf < 4; ++nf) {
            #pragma unroll
            for (int r = 0; r < 4; ++r) {
                int gm = m0 + wr * 64 + mf * 16 + lr4 + r;   // (b,s)
                int gn = n0 + wc * 64 + nf * 16 + lcol;      // (h,e)
                int b = gm >> 11, s = gm & (SB - 1);
                int h = gn >> 6,  e = gn & (HD - 1);
                unsigned short bv = f2bf(acc[mf][nf][r]);
                size_t bh = (size_t)(b * NH + h);
                if (z == 0) qbf[(bh * SB + s) * HD + e] = bv;
                else        vt [(bh * HD + e) * SB + s] = bv;
            }
        }
    }
}

// ---------------- Flash attention: scores = Q Q^T / 8, causal, softmax, @V ----------------
// grid: (32 q-tiles, 32 bh); block 256 = 4 waves, wave owns 16 q-rows; KV tile = 64
__global__ __launch_bounds__(256) void attn_kernel(
    const unsigned short* __restrict__ qbf,  // [32][2048][64]
    const unsigned short* __restrict__ vt,   // [32][64][2048]
    float* __restrict__ out)                 // [2][2048][1024]
{
    __shared__ unsigned short p_lds[4][16][72];  // per-wave P tile, stride 144B (2-way free)
    const int bh  = blockIdx.y;
    const int qb  = blockIdx.x;
    const int wave = threadIdx.x >> 6, lane = threadIdx.x & 63;
    const int lrow = lane & 15, lg = lane >> 4;
    const int q0  = qb * 64;
    const int wq0 = q0 + wave * 16;
    const unsigned short* __restrict__ Qh = qbf + (size_t)bh * SB * HD;
    const unsigned short* __restrict__ Vh = vt  + (size_t)bh * HD * SB;

    // Q A-frags: row = wq0+lrow, k(e) = ks*32 + lg*8
    bf16x8 qf[2];
    #pragma unroll
    for (int ks = 0; ks < 2; ++ks)
        qf[ks] = *reinterpret_cast<const bf16x8*>(Qh + (size_t)(wq0 + lrow) * HD + ks * 32 + lg * 8);

    float m_i[4], l_i[4];
    f32x4 o_acc[4] = {};
    #pragma unroll
    for (int r = 0; r < 4; ++r) { m_i[r] = -INFINITY; l_i[r] = 0.f; }

    for (int t = 0; t <= qb; ++t) {
        const int kv0 = t * 64;
        // S-frags: 4 nf x (16x16), K=64 over 2 mfma
        f32x4 sacc[4];
        #pragma unroll
        for (int nf = 0; nf < 4; ++nf) {
            f32x4 s = {0.f, 0.f, 0.f, 0.f};
            #pragma unroll
            for (int ks = 0; ks < 2; ++ks) {
                bf16x8 bfr = *reinterpret_cast<const bf16x8*>(
                    Qh + (size_t)(kv0 + nf * 16 + lrow) * HD + ks * 32 + lg * 8);
                s = __builtin_amdgcn_mfma_f32_16x16x32_bf16(qf[ks], bfr, s, 0, 0, 0);
            }
            sacc[nf] = s;
        }

        const bool diag = (t == qb);
        float p[4][4];        // [nf][r]
        float rowmax[4] = {-INFINITY, -INFINITY, -INFINITY, -INFINITY};
        #pragma unroll
        for (int nf = 0; nf < 4; ++nf) {
            int col = kv0 + nf * 16 + lrow;
            #pragma unroll
            for (int r = 0; r < 4; ++r) {
                float s = sacc[nf][r] * 0.125f;
                int row = wq0 + lg * 4 + r;
                if (diag && col > row) s = -INFINITY;
                p[nf][r] = s;
                rowmax[r] = fmaxf(rowmax[r], s);
            }
        }
        #pragma unroll
        for (int msk = 1; msk <= 8; msk <<= 1)
            #pragma unroll
            for (int r = 0; r < 4; ++r)
                rowmax[r] = fmaxf(rowmax[r], __shfl_xor(rowmax[r], msk));

        float fac[4];
        #pragma unroll
        for (int r = 0; r < 4; ++r) {
            float mn = fmaxf(m_i[r], rowmax[r]);
            fac[r] = __expf(m_i[r] - mn);      // exp(-inf)=0 on first tile
            m_i[r] = mn;
        }
        float psum[4] = {0.f, 0.f, 0.f, 0.f};
        #pragma unroll
        for (int nf = 0; nf < 4; ++nf)
            #pragma unroll
            for (int r = 0; r < 4; ++r) {
                float e = __expf(p[nf][r] - m_i[r]);   // masked -> 0
                p[nf][r] = e;
                psum[r] += e;
            }
        #pragma unroll
        for (int msk = 1; msk <= 8; msk <<= 1)
            #pragma unroll
            for (int r = 0; r < 4; ++r)
                psum[r] += __shfl_xor(psum[r], msk);
        #pragma unroll
        for (int r = 0; r < 4; ++r)
            l_i[r] = l_i[r] * fac[r] + psum[r];
        #pragma unroll
        for (int ef = 0; ef < 4; ++ef)
            #pragma unroll
            for (int r = 0; r < 4; ++r)
                o_acc[ef][r] *= fac[r];

        // P -> LDS (bf16) to re-layout into A-fragments (within-wave, no barrier needed)
        #pragma unroll
        for (int nf = 0; nf < 4; ++nf)
            #pragma unroll
            for (int r = 0; r < 4; ++r)
                p_lds[wave][lg * 4 + r][nf * 16 + lrow] = f2bf(p[nf][r]);

        // PV: O += P[16x64] @ V[64x64]; B-operand from vt (contiguous along t)
        #pragma unroll
        for (int ks = 0; ks < 2; ++ks) {
            bf16x8 pf = *reinterpret_cast<const bf16x8*>(&p_lds[wave][lrow][ks * 32 + lg * 8]);
            #pragma unroll
            for (int ef = 0; ef < 4; ++ef) {
                bf16x8 vf = *reinterpret_cast<const bf16x8*>(
                    Vh + (size_t)(ef * 16 + lrow) * SB + kv0 + ks * 32 + lg * 8);
                o_acc[ef] = __builtin_amdgcn_mfma_f32_16x16x32_bf16(pf, vf, o_acc[ef], 0, 0, 0);
            }
        }
    }

    // epilogue: out[b][s][h*64+e] = O / l
    const int b = bh >> 4, h = bh & 15;
    #pragma unroll
    for (int r = 0; r < 4; ++r) {
        float inv = 1.f / l_i[r];
        int row = wq0 + lg * 4 + r;
        float* orow = out + ((size_t)b * SB + row) * DD + h * HD;
        #pragma unroll
        for (int ef = 0; ef < 4; ++ef)
            orow[ef * 16 + lrow] = o_acc[ef][r] * inv;
    }
}

extern "C" void kernel_launch(void* const* d_in, const int* in_sizes, int n_in,
                              void* d_out, int out_size, void* d_ws, size_t ws_size,
                              hipStream_t stream) {
    const float* X  = (const float*)d_in[0];
    const float* Wq = (const float*)d_in[1];
    // d_in[2] = Wk: computed-but-unused in the reference output -> skipped
    const float* Wv = (const float*)d_in[3];
    float* out = (float*)d_out;

    unsigned short* qbf = (unsigned short*)d_ws;                   // 32*2048*64 bf16 = 8 MB
    unsigned short* vtp = qbf + (size_t)BH * SB * HD;              // 8 MB

    dim3 g1(DD / BN, (2 * SB) / BM, 2);   // (8, 32, 2)
    proj_kernel<<<g1, dim3(256), 0, stream>>>(X, Wq, Wv, qbf, vtp);

    dim3 g2(SB / 64, BH, 1);              // (32, 32)
    attn_kernel<<<g2, dim3(256), 0, stream>>>(qbf, vtp, out);
}

// Round 2
// 177.039 us; speedup vs baseline: 2.0883x; 2.0883x over previous
//
#include <hip/hip_runtime.h>
#include <hip/hip_bf16.h>

typedef __attribute__((ext_vector_type(4))) float f32x4;
typedef __attribute__((ext_vector_type(8))) short bf16x8;
typedef __attribute__((ext_vector_type(4))) unsigned short u16x4;

// B=2, S=2048, D=1024, H=16, HD=64
#define SB 2048
#define DD 1024
#define NH 16
#define HD 64
#define BH 32   // B*H

static __device__ __forceinline__ unsigned short f2bf(float f) {
    union { float f; unsigned int u; } v; v.f = f;
    unsigned int lsb = (v.u >> 16) & 1u;
    v.u += 0x7fffu + lsb;           // round-to-nearest-even (inputs finite)
    return (unsigned short)(v.u >> 16);
}

// ---------------- Projection GEMM: C[4096,1024] = X[4096,1024] @ W[1024,1024]^T ----------------
// z=0: W=Wq, write qbf[bh][s][e] ; z=1: W=Wv, write vt[bh][e][s]
#define BM 128
#define BN 128
#define BK 32
#define LDP 56   // padded LDS row stride (bf16): 112B, 16B-aligned, 2-way bank alias (free)

__global__ __launch_bounds__(256) void proj_kernel(
    const float* __restrict__ X,
    const float* __restrict__ Wq,
    const float* __restrict__ Wv,
    unsigned short* __restrict__ qbf,   // [32][2048][64]
    unsigned short* __restrict__ vt)    // [32][64][2048]
{
    __shared__ unsigned short As[BM * LDP];
    __shared__ unsigned short Bs[BN * LDP];
    const int z  = blockIdx.z;
    const float* __restrict__ W = z ? Wv : Wq;
    const int m0 = blockIdx.y * BM;
    const int n0 = blockIdx.x * BN;
    const int tid  = threadIdx.x;
    const int wave = tid >> 6;
    const int lane = tid & 63;
    const int wr = wave >> 1, wc = wave & 1;      // 2x2 waves, each owns 64x64
    const int lrow = lane & 15, lk = (lane >> 4) * 8;

    f32x4 acc[4][4] = {};   // [mf][nf]

    for (int k0 = 0; k0 < DD; k0 += BK) {
        #pragma unroll
        for (int p = 0; p < 4; ++p) {
            int idx = p * 256 + tid;       // 0..1023
            int r   = idx >> 3;            // 0..127
            int c4  = (idx & 7) * 4;       // 0..28
            f32x4 a = *reinterpret_cast<const f32x4*>(X + (size_t)(m0 + r) * DD + k0 + c4);
            f32x4 b = *reinterpret_cast<const f32x4*>(W + (size_t)(n0 + r) * DD + k0 + c4);
            u16x4 pa, pb;
            #pragma unroll
            for (int j = 0; j < 4; ++j) { pa[j] = f2bf(a[j]); pb[j] = f2bf(b[j]); }
            *reinterpret_cast<u16x4*>(&As[r * LDP + c4]) = pa;
            *reinterpret_cast<u16x4*>(&Bs[r * LDP + c4]) = pb;
        }
        __syncthreads();

        bf16x8 af[4], bf[4];
        #pragma unroll
        for (int mf = 0; mf < 4; ++mf)
            af[mf] = *reinterpret_cast<const bf16x8*>(&As[(wr * 64 + mf * 16 + lrow) * LDP + lk]);
        #pragma unroll
        for (int nf = 0; nf < 4; ++nf)
            bf[nf] = *reinterpret_cast<const bf16x8*>(&Bs[(wc * 64 + nf * 16 + lrow) * LDP + lk]);
        #pragma unroll
        for (int mf = 0; mf < 4; ++mf)
            #pragma unroll
            for (int nf = 0; nf < 4; ++nf)
                acc[mf][nf] = __builtin_amdgcn_mfma_f32_16x16x32_bf16(af[mf], bf[nf], acc[mf][nf], 0, 0, 0);
        __syncthreads();
    }

    const int lcol = lane & 15, lr4 = (lane >> 4) * 4;
    #pragma unroll
    for (int mf = 0; mf < 4; ++mf) {
        #pragma unroll
        for (int nf = 0; nf < 4; ++nf) {
            #pragma unroll
            for (int r = 0; r < 4; ++r) {
                int gm = m0 + wr * 64 + mf * 16 + lr4 + r;   // (b,s)
                int gn = n0 + wc * 64 + nf * 16 + lcol;      // (h,e)
                int b = gm >> 11, s = gm & (SB - 1);
                int h = gn >> 6,  e = gn & (HD - 1);
                unsigned short bv = f2bf(acc[mf][nf][r]);
                size_t bh = (size_t)(b * NH + h);
                if (z == 0) qbf[(bh * SB + s) * HD + e] = bv;
                else        vt [(bh * HD + e) * SB + s] = bv;
            }
        }
    }
}

// ---------------- Flash attention: scores = Q Q^T / 8, causal, softmax, @V ----------------
// grid: (16 qb-pairs, 32 bh); block 512 = 8 waves.
// Pairing: block handles qb = x and qb = 31-x  -> uniform 33 KV-tiles per block.
// KV-split: wave-group g=0 takes even tiles, g=1 odd tiles; merge partials via LDS.
__global__ __launch_bounds__(512, 4) void attn_kernel(
    const unsigned short* __restrict__ qbf,  // [32][2048][64]
    const unsigned short* __restrict__ vt,   // [32][64][2048]
    float* __restrict__ out)                 // [2][2048][1024]
{
    __shared__ unsigned short p_lds[8][16][72];  // per-wave P tile, stride 144B (2-way free)
    __shared__ float m_s[2][4][16];
    __shared__ float l_s[2][4][16];
    __shared__ float o_s[2][4][16][65];          // +1 pad breaks 4-way bank conflict

    const int bh   = blockIdx.y;
    const int wave = threadIdx.x >> 6, lane = threadIdx.x & 63;
    const int g    = wave >> 2;        // KV parity group
    const int wr   = wave & 3;         // row-group within Q-tile
    const int lrow = lane & 15, lg = lane >> 4;
    const int b = bh >> 4, h = bh & 15;

    const unsigned short* __restrict__ Qh = qbf + (size_t)bh * SB * HD;
    const unsigned short* __restrict__ Vh = vt  + (size_t)bh * HD * SB;

    const int qbs0 = blockIdx.x;
    const int qbs1 = 31 - blockIdx.x;

    for (int pi = 0; pi < 2; ++pi) {
        const int qb  = pi == 0 ? qbs0 : qbs1;
        const int wq0 = qb * 64 + wr * 16;

        // Q A-frags: row = wq0+lrow, k(e) = ks*32 + lg*8
        bf16x8 qf[2];
        #pragma unroll
        for (int ks = 0; ks < 2; ++ks)
            qf[ks] = *reinterpret_cast<const bf16x8*>(Qh + (size_t)(wq0 + lrow) * HD + ks * 32 + lg * 8);

        float m_i[4], l_i[4];
        f32x4 o_acc[4] = {};
        #pragma unroll
        for (int r = 0; r < 4; ++r) { m_i[r] = -INFINITY; l_i[r] = 0.f; }

        // K-fragment prefetch registers for tile t (B-operand rows = KV rows of Q)
        bf16x8 kf[8];
        if (g <= qb) {
            const int kv0 = g * 64;
            #pragma unroll
            for (int nf = 0; nf < 4; ++nf)
                #pragma unroll
                for (int ks = 0; ks < 2; ++ks)
                    kf[nf * 2 + ks] = *reinterpret_cast<const bf16x8*>(
                        Qh + (size_t)(kv0 + nf * 16 + lrow) * HD + ks * 32 + lg * 8);
        }

        for (int t = g; t <= qb; t += 2) {
            const int kv0 = t * 64;
            // QK^T: S-frags from prefetched kf
            f32x4 sacc[4];
            #pragma unroll
            for (int nf = 0; nf < 4; ++nf) {
                f32x4 s = {0.f, 0.f, 0.f, 0.f};
                #pragma unroll
                for (int ks = 0; ks < 2; ++ks)
                    s = __builtin_amdgcn_mfma_f32_16x16x32_bf16(qf[ks], kf[nf * 2 + ks], s, 0, 0, 0);
                sacc[nf] = s;
            }
            // prefetch K-frags for tile t+2 (hides L2 latency under softmax+PV)
            if (t + 2 <= qb) {
                const int kvn = (t + 2) * 64;
                #pragma unroll
                for (int nf = 0; nf < 4; ++nf)
                    #pragma unroll
                    for (int ks = 0; ks < 2; ++ks)
                        kf[nf * 2 + ks] = *reinterpret_cast<const bf16x8*>(
                            Qh + (size_t)(kvn + nf * 16 + lrow) * HD + ks * 32 + lg * 8);
            }

            const bool diag = (t == qb);
            float rowmax[4] = {-INFINITY, -INFINITY, -INFINITY, -INFINITY};
            #pragma unroll
            for (int nf = 0; nf < 4; ++nf) {
                int col = kv0 + nf * 16 + lrow;
                #pragma unroll
                for (int r = 0; r < 4; ++r) {
                    float s = sacc[nf][r] * 0.125f;
                    int row = wq0 + lg * 4 + r;
                    if (diag && col > row) s = -INFINITY;
                    sacc[nf][r] = s;
                    rowmax[r] = fmaxf(rowmax[r], s);
                }
            }
            #pragma unroll
            for (int msk = 1; msk <= 8; msk <<= 1)
                #pragma unroll
                for (int r = 0; r < 4; ++r)
                    rowmax[r] = fmaxf(rowmax[r], __shfl_xor(rowmax[r], msk));

            float fac[4];
            #pragma unroll
            for (int r = 0; r < 4; ++r) {
                float mn = fmaxf(m_i[r], rowmax[r]);
                fac[r] = __expf(m_i[r] - mn);
                m_i[r] = mn;
            }
            float psum[4] = {0.f, 0.f, 0.f, 0.f};
            #pragma unroll
            for (int nf = 0; nf < 4; ++nf)
                #pragma unroll
                for (int r = 0; r < 4; ++r) {
                    float e = __expf(sacc[nf][r] - m_i[r]);
                    sacc[nf][r] = e;
                    psum[r] += e;
                }
            #pragma unroll
            for (int msk = 1; msk <= 8; msk <<= 1)
                #pragma unroll
                for (int r = 0; r < 4; ++r)
                    psum[r] += __shfl_xor(psum[r], msk);
            #pragma unroll
            for (int r = 0; r < 4; ++r)
                l_i[r] = l_i[r] * fac[r] + psum[r];
            #pragma unroll
            for (int ef = 0; ef < 4; ++ef)
                #pragma unroll
                for (int r = 0; r < 4; ++r)
                    o_acc[ef][r] *= fac[r];

            // P -> LDS (bf16) re-layout into A-fragments (within-wave, no barrier)
            #pragma unroll
            for (int nf = 0; nf < 4; ++nf)
                #pragma unroll
                for (int r = 0; r < 4; ++r)
                    p_lds[wave][lg * 4 + r][nf * 16 + lrow] = f2bf(sacc[nf][r]);

            // PV: O += P[16x64] @ V[64x64]
            #pragma unroll
            for (int ks = 0; ks < 2; ++ks) {
                bf16x8 pf = *reinterpret_cast<const bf16x8*>(&p_lds[wave][lrow][ks * 32 + lg * 8]);
                #pragma unroll
                for (int ef = 0; ef < 4; ++ef) {
                    bf16x8 vf = *reinterpret_cast<const bf16x8*>(
                        Vh + (size_t)(ef * 16 + lrow) * SB + kv0 + ks * 32 + lg * 8);
                    o_acc[ef] = __builtin_amdgcn_mfma_f32_16x16x32_bf16(pf, vf, o_acc[ef], 0, 0, 0);
                }
            }
        }

        // ---- merge the two KV-parity partials ----
        #pragma unroll
        for (int ef = 0; ef < 4; ++ef)
            #pragma unroll
            for (int r = 0; r < 4; ++r)
                o_s[g][wr][lg * 4 + r][ef * 16 + lrow] = o_acc[ef][r];
        if (lrow == 0) {
            #pragma unroll
            for (int r = 0; r < 4; ++r) {
                m_s[g][wr][lg * 4 + r] = m_i[r];
                l_s[g][wr][lg * 4 + r] = l_i[r];
            }
        }
        __syncthreads();

        if (g == 0) {
            #pragma unroll
            for (int r = 0; r < 4; ++r) {
                int row = lg * 4 + r;
                float M0 = m_s[0][wr][row], M1 = m_s[1][wr][row];
                float Mx = fmaxf(M0, M1);
                float e0 = __expf(M0 - Mx), e1 = __expf(M1 - Mx);   // exp(-inf)=0
                float L  = l_s[0][wr][row] * e0 + l_s[1][wr][row] * e1;
                float invL = 1.f / L;
                float* orow = out + ((size_t)b * SB + (qb * 64 + wr * 16 + row)) * DD + h * HD;
                #pragma unroll
                for (int ef = 0; ef < 4; ++ef) {
                    int col = ef * 16 + lrow;
                    float o0 = o_s[0][wr][row][col];
                    float o1 = o_s[1][wr][row][col];
                    orow[col] = (o0 * e0 + o1 * e1) * invL;
                }
            }
        }
        __syncthreads();   // protect LDS before next pair half
    }
}

extern "C" void kernel_launch(void* const* d_in, const int* in_sizes, int n_in,
                              void* d_out, int out_size, void* d_ws, size_t ws_size,
                              hipStream_t stream) {
    const float* X  = (const float*)d_in[0];
    const float* Wq = (const float*)d_in[1];
    // d_in[2] = Wk: computed-but-unused in the reference output -> skipped
    const float* Wv = (const float*)d_in[3];
    float* out = (float*)d_out;

    unsigned short* qbf = (unsigned short*)d_ws;                   // 32*2048*64 bf16 = 8 MB
    unsigned short* vtp = qbf + (size_t)BH * SB * HD;              // 8 MB

    dim3 g1(DD / BN, (2 * SB) / BM, 2);   // (8, 32, 2)
    proj_kernel<<<g1, dim3(256), 0, stream>>>(X, Wq, Wv, qbf, vtp);

    dim3 g2(16, BH, 1);                   // 512 uniform blocks
    attn_kernel<<<g2, dim3(512), 0, stream>>>(qbf, vtp, out);
}